// Round 3
// baseline (977.045 us; speedup 1.0000x reference)
//
#include <hip/hip_runtime.h>
#include <hip/hip_bf16.h>
#include <math.h>

// Triangle multiplication (outgoing). N=768, C=128.
// Pipeline:
//   k_convw: f32->bf16 weight conversion (lp,lg,rp,rg,gl,op)
//   k_proj : LN(act) + 5 projections -> left_t/right_t (channel-major bf16), gate (pos-major bf16)
//            v3: no LDS transpose staging (direct 32B-sector stores), 1 barrier, 33KB LDS -> 4 blocks/CU
//   k_tri  : per-channel 768^3 NT GEMM, double-buffered LDS prefetch (2-phase)
//   k_post : LN over c + op-linear + gate -> d_out f32 (256 threads)
// Workspace: 1MB weights + 4 * 151MB bf16 buffers ~= 605MB.

#define NRES 768
#define CD 128
#define NN (768 * 768)

typedef unsigned short u16;
typedef unsigned int u32;
typedef __attribute__((ext_vector_type(8))) short bf16x8;
typedef __attribute__((ext_vector_type(4))) float f32x4;

__device__ __forceinline__ float b2f(u16 u) {
  union { u32 i; float f; } v; v.i = ((u32)u) << 16; return v.f;
}
__device__ __forceinline__ u16 f2bf(float f) {
  __hip_bfloat16 h = __float2bfloat16(f);   // native cvt; compiler can pair into v_cvt_pk_bf16_f32
  return *reinterpret_cast<u16*>(&h);
}
__device__ __forceinline__ float sigm(float x) {
  return __builtin_amdgcn_rcpf(1.0f + __builtin_amdgcn_exp2f(x * -1.44269504f));
}

__device__ __forceinline__ void async16(u16* lds, const u16* g) {
  __builtin_amdgcn_global_load_lds((const __attribute__((address_space(1))) void*)g,
                                   (__attribute__((address_space(3))) void*)lds, 16, 0, 0);
}

// ---------------- K0: weight conversion ----------------
__global__ void k_convw(const float* __restrict__ a, const float* __restrict__ b,
                        const float* __restrict__ c, const float* __restrict__ d,
                        const float* __restrict__ e, const float* __restrict__ f,
                        u16* __restrict__ wb) {
  int i = blockIdx.x * 256 + threadIdx.x;
  int m = i >> 14, r = i & 16383;
  const float* s = (m == 0) ? a : (m == 1) ? b : (m == 2) ? c : (m == 3) ? d : (m == 4) ? e : f;
  wb[i] = f2bf(s[r]);
}

// ---------------- K1: LN + 5 projections (128-row tile, barrier-free passes) ----------------
__global__ __launch_bounds__(256, 4) void k_proj(
    const float* __restrict__ act, const float* __restrict__ mask,
    const float* __restrict__ lnw, const float* __restrict__ lnb,
    const u16* __restrict__ wb,
    const float* __restrict__ lpb, const float* __restrict__ lgb,
    const float* __restrict__ rpb, const float* __restrict__ rgb,
    const float* __restrict__ glb,
    u16* __restrict__ left_t, u16* __restrict__ right_t, u16* __restrict__ gate) {
  __shared__ u16 sx[128][128];   // act_ln, XOR-swizzled (key=(row&7)<<3 in u16 units)
  __shared__ float fmask[128];
  const int t = threadIdx.x;
  const int pos0 = blockIdx.x * 128;
  const int l = t & 63, w = t >> 6;
  const int lr = l & 15, g4 = l >> 4;

  // ---- phase 1: LayerNorm, 2 threads per row (64 ch each)
  {
    const int r = t >> 1, q = t & 1;
    const float* arow = act + (size_t)(pos0 + r) * CD + q * 64;
    float4 xv[16];
    float s = 0.f, ss = 0.f;
#pragma unroll
    for (int j = 0; j < 16; ++j) {
      xv[j] = *(const float4*)(arow + j * 4);
      s += xv[j].x + xv[j].y + xv[j].z + xv[j].w;
      ss += xv[j].x * xv[j].x + xv[j].y * xv[j].y + xv[j].z * xv[j].z + xv[j].w * xv[j].w;
    }
    s += __shfl_xor(s, 1); ss += __shfl_xor(ss, 1);
    float mu = s * (1.0f / CD);
    float rs = rsqrtf(ss * (1.0f / CD) - mu * mu + 1e-5f);
    const int key = (r & 7) << 3;
#pragma unroll
    for (int j = 0; j < 16; j += 2) {
      u16 o[8] __attribute__((aligned(16)));
      const float* xx = (const float*)&xv[j];
      int c0 = q * 64 + j * 4;
#pragma unroll
      for (int e2 = 0; e2 < 8; ++e2)
        o[e2] = f2bf((xx[e2] - mu) * rs * lnw[c0 + e2] + lnb[c0 + e2]);
      *(bf16x8*)&sx[r][c0 ^ key] = *(const bf16x8*)o;
    }
    if (t < 128) fmask[t] = mask[pos0 + t];
  }
  __syncthreads();
  // sx is read-only from here on: NO further barriers in this kernel.

  // ---- pair projection: wave w owns d in [w*32, w*32+32); direct channel-major stores
  auto pair_pass = [&](const u16* __restrict__ WP, const u16* __restrict__ WG,
                       const float* __restrict__ bP, const float* __restrict__ bG,
                       u16* __restrict__ dst) {
    bf16x8 bp[2][4], bg[2][4];
    float biasP[2], biasG[2];
    int dd[2];
#pragma unroll
    for (int c2 = 0; c2 < 2; ++c2) {
      dd[c2] = w * 32 + c2 * 16 + lr;
#pragma unroll
      for (int kk = 0; kk < 4; ++kk) {
        bp[c2][kk] = *(const bf16x8*)&WP[dd[c2] * CD + kk * 32 + g4 * 8];
        bg[c2][kk] = *(const bf16x8*)&WG[dd[c2] * CD + kk * 32 + g4 * 8];
      }
      biasP[c2] = bP[dd[c2]];
      biasG[c2] = bG[dd[c2]];
    }
#pragma unroll
    for (int mc = 0; mc < 2; ++mc) {
#pragma unroll
      for (int m = 0; m < 4; ++m) {
        const int row = mc * 64 + m * 16 + lr;
        const int key = (row & 7) << 3;
        bf16x8 af[4];
#pragma unroll
        for (int kk = 0; kk < 4; ++kk)
          af[kk] = *(const bf16x8*)&sx[row][(kk * 32 + g4 * 8) ^ key];
        const int rowc = m * 16 + g4 * 4;
        float fm[4];
#pragma unroll
        for (int r = 0; r < 4; ++r) fm[r] = fmask[mc * 64 + rowc + r];
#pragma unroll
        for (int c2 = 0; c2 < 2; ++c2) {
          f32x4 aP = {0.f, 0.f, 0.f, 0.f}, aG = {0.f, 0.f, 0.f, 0.f};
#pragma unroll
          for (int kk = 0; kk < 4; ++kk) {
            aP = __builtin_amdgcn_mfma_f32_16x16x32_bf16(af[kk], bp[c2][kk], aP, 0, 0, 0);
            aG = __builtin_amdgcn_mfma_f32_16x16x32_bf16(af[kk], bg[c2][kk], aG, 0, 0, 0);
          }
          u16 o[4] __attribute__((aligned(8)));
#pragma unroll
          for (int r = 0; r < 4; ++r)
            o[r] = f2bf((aP[r] + biasP[c2]) * sigm(aG[r] + biasG[c2]) * fm[r]);
          // 4 lanes (g4) x 8B contiguous => one aligned 32B sector per d
          *(uint2*)&dst[(size_t)dd[c2] * NN + pos0 + mc * 64 + rowc] = *(const uint2*)o;
        }
      }
    }
  };

  pair_pass(wb, wb + 16384, lpb, lgb, left_t);
  pair_pass(wb + 2 * 16384, wb + 3 * 16384, rpb, rgb, right_t);

  // ---- gate: single matrix, pos-major output (scalar u16 stores, 32B segments/16-lane group)
  {
    const u16* WG = wb + 4 * 16384;
    bf16x8 bg[2][4];
    float biasG[2];
    int dd[2];
#pragma unroll
    for (int c2 = 0; c2 < 2; ++c2) {
      dd[c2] = w * 32 + c2 * 16 + lr;
#pragma unroll
      for (int kk = 0; kk < 4; ++kk)
        bg[c2][kk] = *(const bf16x8*)&WG[dd[c2] * CD + kk * 32 + g4 * 8];
      biasG[c2] = glb[dd[c2]];
    }
#pragma unroll
    for (int mc = 0; mc < 2; ++mc) {
#pragma unroll
      for (int m = 0; m < 4; ++m) {
        const int row = mc * 64 + m * 16 + lr;
        const int key = (row & 7) << 3;
        bf16x8 af[4];
#pragma unroll
        for (int kk = 0; kk < 4; ++kk)
          af[kk] = *(const bf16x8*)&sx[row][(kk * 32 + g4 * 8) ^ key];
        const int posb = pos0 + mc * 64 + m * 16 + g4 * 4;
#pragma unroll
        for (int c2 = 0; c2 < 2; ++c2) {
          f32x4 aG = {0.f, 0.f, 0.f, 0.f};
#pragma unroll
          for (int kk = 0; kk < 4; ++kk)
            aG = __builtin_amdgcn_mfma_f32_16x16x32_bf16(af[kk], bg[c2][kk], aG, 0, 0, 0);
#pragma unroll
          for (int r = 0; r < 4; ++r)
            gate[(size_t)(posb + r) * CD + dd[c2]] = f2bf(sigm(aG[r] + biasG[c2]));
        }
      }
    }
  }
}

// ---------------- K2: per-channel triangle GEMM (double-buffered prefetch) ----------------
__global__ __launch_bounds__(256, 4) void k_tri(
    const u16* __restrict__ left_t, const u16* __restrict__ right_t,
    u16* __restrict__ out_t) {
  __shared__ u16 sA[2][128 * 32];
  __shared__ u16 sB[2][128 * 32];
  const int t = threadIdx.x, l = t & 63, w = t >> 6;
  const int bid = blockIdx.x;
  const int xcd = bid & 7, idx = bid >> 3;
  const int c = xcd * 16 + idx / 36;
  const int tile = idx - (idx / 36) * 36;
  const int ti = tile / 6, tj = tile - (tile / 6) * 6;
  const u16* A = left_t + (size_t)c * NN + (size_t)ti * 128 * NRES;
  const u16* B = right_t + (size_t)c * NN + (size_t)tj * 128 * NRES;
  const int lr = l & 15, lk = (l >> 4) * 8;
  const int wr = (w >> 1) * 64, wc = (w & 1) * 64;
  const int wbase = t & ~63;
  f32x4 acc[4][4];
#pragma unroll
  for (int m = 0; m < 4; ++m)
#pragma unroll
    for (int n = 0; n < 4; ++n) acc[m][n] = (f32x4){0.f, 0.f, 0.f, 0.f};

  auto stage = [&](int p, int k0) {
#pragma unroll
    for (int it = 0; it < 2; ++it) {
      int li = it * 256 + t;
      async16(&sA[p][(it * 256 + wbase) * 8], A + (size_t)(li >> 2) * NRES + k0 + (li & 3) * 8);
      async16(&sB[p][(it * 256 + wbase) * 8], B + (size_t)(li >> 2) * NRES + k0 + (li & 3) * 8);
    }
  };

  stage(0, 0);
  __syncthreads();
  for (int ks = 0; ks < 24; ++ks) {
    const int p = ks & 1;
    if (ks < 23) stage(p ^ 1, (ks + 1) * 32);   // prefetch issued BEFORE compute
    bf16x8 av[4], bv[4];
#pragma unroll
    for (int m = 0; m < 4; ++m) av[m] = *(const bf16x8*)&sA[p][(wr + m * 16 + lr) * 32 + lk];
#pragma unroll
    for (int n = 0; n < 4; ++n) bv[n] = *(const bf16x8*)&sB[p][(wc + n * 16 + lr) * 32 + lk];
#pragma unroll
    for (int m = 0; m < 4; ++m)
#pragma unroll
      for (int n = 0; n < 4; ++n)
        acc[m][n] = __builtin_amdgcn_mfma_f32_16x16x32_bf16(av[m], bv[n], acc[m][n], 0, 0, 0);
    __syncthreads();   // drains prefetch vmcnt; next iter reads buf p^1
  }

  u16* O = out_t + (size_t)c * NN;
  const int r0l = (l >> 4) << 2;
#pragma unroll
  for (int m = 0; m < 4; ++m) {
#pragma unroll
    for (int n = 0; n < 4; ++n) {
      int row = ti * 128 + wr + m * 16 + r0l;
      int col = tj * 128 + wc + n * 16 + lr;
#pragma unroll
      for (int r = 0; r < 4; ++r)
        O[(size_t)(row + r) * NRES + col] = f2bf(acc[m][n][r]);
    }
  }
}

// ---------------- K3: LN + op-linear + gate (256 threads) ----------------
__global__ __launch_bounds__(256, 4) void k_post(
    const u16* __restrict__ out_t, const u16* __restrict__ gate,
    const float* __restrict__ clnw, const float* __restrict__ clnb,
    const u16* __restrict__ wop, const float* __restrict__ opb,
    float* __restrict__ out) {
  __shared__ u16 sx[128][136];
  __shared__ float smu[128], srs[128];
  __shared__ float swv[128], sbv[128];
  const int t = threadIdx.x;
  const int pos0 = blockIdx.x * 128;

  if (t < 128) { swv[t] = clnw[t]; sbv[t] = clnb[t]; }

  // phase A: 2 threads per position (64 ch each); coalesced strided reads
  {
    const int r = t >> 1, q = t & 1;
    const size_t p = (size_t)pos0 + r;
    float s = 0.f, ss = 0.f;
    const int key = ((r >> 3) & 7) << 4;
#pragma unroll
    for (int ch = 0; ch < 8; ++ch) {
      const int c0 = q * 64 + ch * 8;
      u16 u[8] __attribute__((aligned(16)));
#pragma unroll
      for (int e = 0; e < 8; ++e) u[e] = out_t[(size_t)(c0 + e) * NN + p];
#pragma unroll
      for (int e = 0; e < 8; ++e) { float f = b2f(u[e]); s += f; ss += f * f; }
      *(bf16x8*)&sx[r][c0 ^ key] = *(const bf16x8*)u;
    }
    s += __shfl_xor(s, 1); ss += __shfl_xor(ss, 1);
    float mu = s * (1.0f / CD);
    float rs = rsqrtf(ss * (1.0f / CD) - mu * mu + 1e-5f);
    if (q == 0) { smu[r] = mu; srs[r] = rs; }
  }
  __syncthreads();

  // phase C: 4 waves; wave w owns rows [w*32, w*32+32)
  const int l = t & 63, w = t >> 6;
  const int lr = l & 15, lk8 = (l >> 4) * 8;
  bf16x8 af[2][4];
#pragma unroll
  for (int m = 0; m < 2; ++m) {
    const int pr = w * 32 + m * 16 + lr;
    const float mu = smu[pr], rs = srs[pr];
    const int key = ((pr >> 3) & 7) << 4;
#pragma unroll
    for (int kk = 0; kk < 4; ++kk) {
      const int c0 = kk * 32 + lk8;
      bf16x8 raw = *(const bf16x8*)&sx[pr][c0 ^ key];
      u16 o[8] __attribute__((aligned(16)));
#pragma unroll
      for (int e = 0; e < 8; ++e)
        o[e] = f2bf((b2f((u16)raw[e]) - mu) * rs * swv[c0 + e] + sbv[c0 + e]);
      af[m][kk] = *(const bf16x8*)o;
    }
  }
  const int r0l = (l >> 4) << 2;
#pragma unroll
  for (int ct = 0; ct < 8; ++ct) {
    const int d = ct * 16 + lr;
    bf16x8 bv[4];
#pragma unroll
    for (int kk = 0; kk < 4; ++kk)
      bv[kk] = *(const bf16x8*)&wop[d * CD + kk * 32 + lk8];
    const float bo = opb[d];
#pragma unroll
    for (int m = 0; m < 2; ++m) {
      f32x4 acc = {0.f, 0.f, 0.f, 0.f};
#pragma unroll
      for (int kk = 0; kk < 4; ++kk)
        acc = __builtin_amdgcn_mfma_f32_16x16x32_bf16(af[m][kk], bv[kk], acc, 0, 0, 0);
      const int prow = w * 32 + m * 16 + r0l;
#pragma unroll
      for (int r = 0; r < 4; ++r) {
        size_t pp = (size_t)(pos0 + prow + r) * CD + d;
        out[pp] = (acc[r] + bo) * b2f(gate[pp]);
      }
    }
  }
}

extern "C" void kernel_launch(void* const* d_in, const int* in_sizes, int n_in,
                              void* d_out, int out_size, void* d_ws, size_t ws_size,
                              hipStream_t stream) {
  (void)in_sizes; (void)n_in; (void)out_size; (void)ws_size;
  const float* act  = (const float*)d_in[0];
  const float* mask = (const float*)d_in[1];
  const float* lnw  = (const float*)d_in[2];
  const float* lnb  = (const float*)d_in[3];
  const float* lpw  = (const float*)d_in[4];
  const float* lpb  = (const float*)d_in[5];
  const float* rpw  = (const float*)d_in[6];
  const float* rpb  = (const float*)d_in[7];
  const float* lgw  = (const float*)d_in[8];
  const float* lgb  = (const float*)d_in[9];
  const float* rgw  = (const float*)d_in[10];
  const float* rgb  = (const float*)d_in[11];
  const float* clnw = (const float*)d_in[12];
  const float* clnb = (const float*)d_in[13];
  const float* opw  = (const float*)d_in[14];
  const float* opb  = (const float*)d_in[15];
  const float* glw  = (const float*)d_in[16];
  const float* glb  = (const float*)d_in[17];

  char* wsb = (char*)d_ws;
  u16* wb = (u16*)wsb;                       // 6 * 16384 * 2B = 196KB
  const size_t SZ = (size_t)NN * CD * 2;     // 151MB
  size_t off = (size_t)1 << 20;
  u16* left_t  = (u16*)(wsb + off); off += SZ;
  u16* right_t = (u16*)(wsb + off); off += SZ;
  u16* gate    = (u16*)(wsb + off); off += SZ;
  u16* out_t   = (u16*)(wsb + off); off += SZ;

  k_convw<<<384, 256, 0, stream>>>(lpw, lgw, rpw, rgw, glw, opw, wb);
  k_proj<<<NN / 128, 256, 0, stream>>>(act, mask, lnw, lnb, wb,
                                       lpb, lgb, rpb, rgb, glb,
                                       left_t, right_t, gate);
  k_tri<<<4608, 256, 0, stream>>>(left_t, right_t, out_t);
  k_post<<<NN / 128, 256, 0, stream>>>(out_t, gate, clnw, clnb,
                                       wb + 5 * 16384, opb, (float*)d_out);
}

// Round 7
// 746.770 us; speedup vs baseline: 1.3084x; 1.3084x over previous
//
#include <hip/hip_runtime.h>
#include <hip/hip_bf16.h>
#include <math.h>

// Triangle multiplication (outgoing). N=768, C=128.
// Pipeline:
//   k_convw: f32->bf16 weight conversion (lp,lg,rp,rg,gl,op)
//   k_proj : LN(act) + 5 projections -> left_t/right_t (channel-major bf16), gate (pos-major bf16)
//            LDS-staged output dumps (direct 32B bf16 stores cause HBM RMW: WRITE 442MB->1.23GB, v3)
//   k_tri  : per-channel 768^3 NT GEMM -> out in F32 (removes dominant bf16 rounding of the
//            largest intermediate). f32 out (302MB) aliases: ch 0-63 -> o1 slot; ch 64-95 ->
//            left_t first half; ch 96-127 -> right_t first half. Two launches so writes only
//            touch regions whose readers (prior launch) already completed.
//   k_post : f32 LN over c + op-linear + gate -> d_out f32 (64-pos tiles, f32 stats in regs)
//            v7 fix: clnw/clnb read directly from global in phase A (the LDS copy was consumed
//            before any barrier -> race; threads 128-255 read uninitialized LDS).
// Workspace: 1MB weights + 4 * 151MB buffers = 605MB total.

#define NRES 768
#define CD 128
#define NN (768 * 768)

typedef unsigned short u16;
typedef unsigned int u32;
typedef __attribute__((ext_vector_type(8))) short bf16x8;
typedef __attribute__((ext_vector_type(4))) float f32x4;

__device__ __forceinline__ float b2f(u16 u) {
  union { u32 i; float f; } v; v.i = ((u32)u) << 16; return v.f;
}
__device__ __forceinline__ u16 f2bf(float f) {
  __hip_bfloat16 h = __float2bfloat16(f);
  return *reinterpret_cast<u16*>(&h);
}
__device__ __forceinline__ float sigm(float x) {
  return __builtin_amdgcn_rcpf(1.0f + __builtin_amdgcn_exp2f(x * -1.44269504f));
}

__device__ __forceinline__ void async16(u16* lds, const u16* g) {
  __builtin_amdgcn_global_load_lds((const __attribute__((address_space(1))) void*)g,
                                   (__attribute__((address_space(3))) void*)lds, 16, 0, 0);
}

// ---------------- K0: weight conversion ----------------
__global__ void k_convw(const float* __restrict__ a, const float* __restrict__ b,
                        const float* __restrict__ c, const float* __restrict__ d,
                        const float* __restrict__ e, const float* __restrict__ f,
                        u16* __restrict__ wb) {
  int i = blockIdx.x * 256 + threadIdx.x;
  int m = i >> 14, r = i & 16383;
  const float* s = (m == 0) ? a : (m == 1) ? b : (m == 2) ? c : (m == 3) ? d : (m == 4) ? e : f;
  wb[i] = f2bf(s[r]);
}

// ---------------- K1: LN + 5 projections (128-row tile, LDS-staged dumps) ----------------
__global__ __launch_bounds__(256, 3) void k_proj(
    const float* __restrict__ act, const float* __restrict__ mask,
    const float* __restrict__ lnw, const float* __restrict__ lnb,
    const u16* __restrict__ wb,
    const float* __restrict__ lpb, const float* __restrict__ lgb,
    const float* __restrict__ rpb, const float* __restrict__ rgb,
    const float* __restrict__ glb,
    u16* __restrict__ left_t, u16* __restrict__ right_t, u16* __restrict__ gate) {
  __shared__ u16 sx[128][128];   // act_ln, XOR-swizzled (key=(row&7)<<3 in u16 units)
  __shared__ u16 stb[128 * 72];  // staging: pair=[128 d][stride 72]; gate=[64 pos][stride 136]
  __shared__ float fmask[128];
  const int t = threadIdx.x;
  const int pos0 = blockIdx.x * 128;
  const int l = t & 63, w = t >> 6;
  const int lr = l & 15, g4 = l >> 4;

  // ---- phase 1: LayerNorm, 2 threads per row (64 ch each)
  {
    const int r = t >> 1, q = t & 1;
    const float* arow = act + (size_t)(pos0 + r) * CD + q * 64;
    float4 xv[16];
    float s = 0.f, ss = 0.f;
#pragma unroll
    for (int j = 0; j < 16; ++j) {
      xv[j] = *(const float4*)(arow + j * 4);
      s += xv[j].x + xv[j].y + xv[j].z + xv[j].w;
      ss += xv[j].x * xv[j].x + xv[j].y * xv[j].y + xv[j].z * xv[j].z + xv[j].w * xv[j].w;
    }
    s += __shfl_xor(s, 1); ss += __shfl_xor(ss, 1);
    float mu = s * (1.0f / CD);
    float rs = rsqrtf(ss * (1.0f / CD) - mu * mu + 1e-5f);
    const int key = (r & 7) << 3;
#pragma unroll
    for (int j = 0; j < 16; j += 2) {
      u16 o[8] __attribute__((aligned(16)));
      const float* xx = (const float*)&xv[j];
      int c0 = q * 64 + j * 4;
#pragma unroll
      for (int e2 = 0; e2 < 8; ++e2)
        o[e2] = f2bf((xx[e2] - mu) * rs * lnw[c0 + e2] + lnb[c0 + e2]);
      *(bf16x8*)&sx[r][c0 ^ key] = *(const bf16x8*)o;
    }
    if (t < 128) fmask[t] = mask[pos0 + t];
  }
  __syncthreads();

  // ---- pair projection: wave w owns d in [w*32, w*32+32); staged channel-major dumps
  auto pair_pass = [&](const u16* __restrict__ WP, const u16* __restrict__ WG,
                       const float* __restrict__ bP, const float* __restrict__ bG,
                       u16* __restrict__ dst) {
    bf16x8 bp[2][4], bg[2][4];
    float biasP[2], biasG[2];
    int dd[2];
#pragma unroll
    for (int c2 = 0; c2 < 2; ++c2) {
      dd[c2] = w * 32 + c2 * 16 + lr;
#pragma unroll
      for (int kk = 0; kk < 4; ++kk) {
        bp[c2][kk] = *(const bf16x8*)&WP[dd[c2] * CD + kk * 32 + g4 * 8];
        bg[c2][kk] = *(const bf16x8*)&WG[dd[c2] * CD + kk * 32 + g4 * 8];
      }
      biasP[c2] = bP[dd[c2]];
      biasG[c2] = bG[dd[c2]];
    }
#pragma unroll
    for (int mc = 0; mc < 2; ++mc) {
#pragma unroll
      for (int m = 0; m < 4; ++m) {
        const int row = mc * 64 + m * 16 + lr;
        const int key = (row & 7) << 3;
        bf16x8 af[4];
#pragma unroll
        for (int kk = 0; kk < 4; ++kk)
          af[kk] = *(const bf16x8*)&sx[row][(kk * 32 + g4 * 8) ^ key];
        const int rowc = m * 16 + g4 * 4;
        float fm[4];
#pragma unroll
        for (int r = 0; r < 4; ++r) fm[r] = fmask[mc * 64 + rowc + r];
#pragma unroll
        for (int c2 = 0; c2 < 2; ++c2) {
          f32x4 aP = {0.f, 0.f, 0.f, 0.f}, aG = {0.f, 0.f, 0.f, 0.f};
#pragma unroll
          for (int kk = 0; kk < 4; ++kk) {
            aP = __builtin_amdgcn_mfma_f32_16x16x32_bf16(af[kk], bp[c2][kk], aP, 0, 0, 0);
            aG = __builtin_amdgcn_mfma_f32_16x16x32_bf16(af[kk], bg[c2][kk], aG, 0, 0, 0);
          }
          u16 o[4] __attribute__((aligned(8)));
#pragma unroll
          for (int r = 0; r < 4; ++r)
            o[r] = f2bf((aP[r] + biasP[c2]) * sigm(aG[r] + biasG[c2]) * fm[r]);
          *(uint2*)&stb[dd[c2] * 72 + rowc] = *(const uint2*)o;
        }
      }
      __syncthreads();
      // dump 64-pos chunk: 8 lanes per d-row => 128B contiguous global store group
#pragma unroll
      for (int p = 0; p < 4; ++p) {
        const int d = p * 32 + (t >> 3), off = (t & 7) * 8;
        *(bf16x8*)&dst[(size_t)d * NN + pos0 + mc * 64 + off] = *(const bf16x8*)&stb[d * 72 + off];
      }
      __syncthreads();
    }
  };

  pair_pass(wb, wb + 16384, lpb, lgb, left_t);
  pair_pass(wb + 2 * 16384, wb + 3 * 16384, rpb, rgb, right_t);

  // ---- gate: single matrix, pos-major output, staged as [64 pos][stride 136]
  {
    const u16* WG = wb + 4 * 16384;
    bf16x8 bg[2][4];
    float biasG[2];
    int dd[2];
#pragma unroll
    for (int c2 = 0; c2 < 2; ++c2) {
      dd[c2] = w * 32 + c2 * 16 + lr;
#pragma unroll
      for (int kk = 0; kk < 4; ++kk)
        bg[c2][kk] = *(const bf16x8*)&WG[dd[c2] * CD + kk * 32 + g4 * 8];
      biasG[c2] = glb[dd[c2]];
    }
#pragma unroll
    for (int mc = 0; mc < 2; ++mc) {
#pragma unroll
      for (int m = 0; m < 4; ++m) {
        const int row = mc * 64 + m * 16 + lr;
        const int key = (row & 7) << 3;
        bf16x8 af[4];
#pragma unroll
        for (int kk = 0; kk < 4; ++kk)
          af[kk] = *(const bf16x8*)&sx[row][(kk * 32 + g4 * 8) ^ key];
        const int rowc = m * 16 + g4 * 4;
#pragma unroll
        for (int c2 = 0; c2 < 2; ++c2) {
          f32x4 aG = {0.f, 0.f, 0.f, 0.f};
#pragma unroll
          for (int kk = 0; kk < 4; ++kk)
            aG = __builtin_amdgcn_mfma_f32_16x16x32_bf16(af[kk], bg[c2][kk], aG, 0, 0, 0);
#pragma unroll
          for (int r = 0; r < 4; ++r)
            stb[(rowc + r) * 136 + dd[c2]] = f2bf(sigm(aG[r] + biasG[c2]));   // stride 136 >= 128
        }
      }
      __syncthreads();
      {
        const int row = t >> 2, dc = (t & 3) * 32;
#pragma unroll
        for (int jj = 0; jj < 4; ++jj)
          *(bf16x8*)&gate[(size_t)(pos0 + mc * 64 + row) * CD + dc + jj * 8] =
              *(const bf16x8*)&stb[row * 136 + dc + jj * 8];
      }
      __syncthreads();
    }
  }
}

// ---------------- K2: per-channel triangle GEMM, f32 output, split launch ----------------
__global__ __launch_bounds__(256, 4) void k_tri(
    const u16* __restrict__ left_t, const u16* __restrict__ right_t,
    float* __restrict__ o1, float* __restrict__ o2, float* __restrict__ o3,
    int cbase) {
  __shared__ u16 sA[2][128 * 32];
  __shared__ u16 sB[2][128 * 32];
  const int t = threadIdx.x, l = t & 63, w = t >> 6;
  const int bid = blockIdx.x;                 // 2304 blocks: 64 ch x 36 tiles
  const int xcd = bid & 7, idx = bid >> 3;    // idx in [0,288)
  const int c = cbase + xcd * 8 + idx / 36;
  const int tile = idx - (idx / 36) * 36;
  const int ti = tile / 6, tj = tile - (tile / 6) * 6;
  const u16* A = left_t + (size_t)c * NN + (size_t)ti * 128 * NRES;
  const u16* B = right_t + (size_t)c * NN + (size_t)tj * 128 * NRES;
  const int lr = l & 15, lk = (l >> 4) * 8;
  const int wr = (w >> 1) * 64, wc = (w & 1) * 64;
  const int wbase = t & ~63;
  f32x4 acc[4][4];
#pragma unroll
  for (int m = 0; m < 4; ++m)
#pragma unroll
    for (int n = 0; n < 4; ++n) acc[m][n] = (f32x4){0.f, 0.f, 0.f, 0.f};

  auto stage = [&](int p, int k0) {
#pragma unroll
    for (int it = 0; it < 2; ++it) {
      int li = it * 256 + t;
      async16(&sA[p][(it * 256 + wbase) * 8], A + (size_t)(li >> 2) * NRES + k0 + (li & 3) * 8);
      async16(&sB[p][(it * 256 + wbase) * 8], B + (size_t)(li >> 2) * NRES + k0 + (li & 3) * 8);
    }
  };

  stage(0, 0);
  __syncthreads();
  for (int ks = 0; ks < 24; ++ks) {
    const int p = ks & 1;
    if (ks < 23) stage(p ^ 1, (ks + 1) * 32);   // prefetch issued BEFORE compute
    bf16x8 av[4], bv[4];
#pragma unroll
    for (int m = 0; m < 4; ++m) av[m] = *(const bf16x8*)&sA[p][(wr + m * 16 + lr) * 32 + lk];
#pragma unroll
    for (int n = 0; n < 4; ++n) bv[n] = *(const bf16x8*)&sB[p][(wc + n * 16 + lr) * 32 + lk];
#pragma unroll
    for (int m = 0; m < 4; ++m)
#pragma unroll
      for (int n = 0; n < 4; ++n)
        acc[m][n] = __builtin_amdgcn_mfma_f32_16x16x32_bf16(av[m], bv[n], acc[m][n], 0, 0, 0);
    __syncthreads();   // drains prefetch vmcnt; next iter reads buf p^1
  }

  // f32 output region select (ch 0-63 -> o1; 64-95 -> o2; 96-127 -> o3)
  float* O = (c < 64) ? (o1 + (size_t)c * NN)
           : (c < 96) ? (o2 + (size_t)(c - 64) * NN)
                      : (o3 + (size_t)(c - 96) * NN);
  const int r0l = (l >> 4) << 2;
#pragma unroll
  for (int m = 0; m < 4; ++m) {
#pragma unroll
    for (int n = 0; n < 4; ++n) {
      int row = ti * 128 + wr + m * 16 + r0l;
      int col = tj * 128 + wc + n * 16 + lr;
#pragma unroll
      for (int r = 0; r < 4; ++r)
        O[(size_t)(row + r) * NRES + col] = acc[m][n][r];   // 16 lanes x 4B = aligned 64B lines
    }
  }
}

// ---------------- K3: f32 LN + op-linear + gate (64-pos tiles) ----------------
__global__ __launch_bounds__(256, 4) void k_post(
    const float* __restrict__ o1, const float* __restrict__ o2, const float* __restrict__ o3,
    const u16* __restrict__ gate,
    const float* __restrict__ clnw, const float* __restrict__ clnb,
    const u16* __restrict__ wop, const float* __restrict__ opb,
    float* __restrict__ out) {
  __shared__ u16 sx[64][128];    // normalized bf16, XOR-swizzled (key=(row&7)<<3)
  const int t = threadIdx.x;
  const int pos0 = blockIdx.x * 64;

  // phase A: 4 threads per position, 32 channels each; f32 stats + single bf16 rounding.
  // clnw/clnb read DIRECTLY from global (512B, L1-resident) — no pre-barrier LDS use.
  {
    const int r = t >> 2, q = t & 3;
    const size_t p = (size_t)pos0 + r;
    const float* base = (q == 0) ? o1
                      : (q == 1) ? (o1 + (size_t)32 * NN)
                      : (q == 2) ? o2 : o3;
    float x[32];
    float s = 0.f, ss = 0.f;
#pragma unroll
    for (int cc = 0; cc < 32; ++cc) {
      x[cc] = base[(size_t)cc * NN + p];
      s += x[cc];
      ss += x[cc] * x[cc];
    }
    s += __shfl_xor(s, 1); ss += __shfl_xor(ss, 1);
    s += __shfl_xor(s, 2); ss += __shfl_xor(ss, 2);
    const float mu = s * (1.0f / CD);
    const float rs = rsqrtf(ss * (1.0f / CD) - mu * mu + 1e-5f);
    const int key = (r & 7) << 3;
#pragma unroll
    for (int cc = 0; cc < 32; cc += 4) {
      const int c0 = q * 32 + cc;
      const float4 wv = *(const float4*)&clnw[c0];
      const float4 bv = *(const float4*)&clnb[c0];
      u16 o[4] __attribute__((aligned(8)));
      o[0] = f2bf((x[cc + 0] - mu) * rs * wv.x + bv.x);
      o[1] = f2bf((x[cc + 1] - mu) * rs * wv.y + bv.y);
      o[2] = f2bf((x[cc + 2] - mu) * rs * wv.z + bv.z);
      o[3] = f2bf((x[cc + 3] - mu) * rs * wv.w + bv.w);
      *(uint2*)&sx[r][c0 ^ key] = *(const uint2*)o;   // c0 multiple of 4; key flips bits 3-5 only... 
    }
  }
  __syncthreads();

  // phase C: wave w owns rows [w*16, w*16+16)
  const int l = t & 63, w = t >> 6;
  const int lr = l & 15, lk8 = (l >> 4) * 8;
  const int row = w * 16 + lr;
  const int key = (row & 7) << 3;
  bf16x8 af[4];
#pragma unroll
  for (int kk = 0; kk < 4; ++kk)
    af[kk] = *(const bf16x8*)&sx[row][(kk * 32 + lk8) ^ key];
  const int r0l = (l >> 4) << 2;
#pragma unroll
  for (int ct = 0; ct < 8; ++ct) {
    const int d = ct * 16 + lr;
    bf16x8 bv[4];
#pragma unroll
    for (int kk = 0; kk < 4; ++kk)
      bv[kk] = *(const bf16x8*)&wop[d * CD + kk * 32 + lk8];
    const float bo = opb[d];
    f32x4 acc = {0.f, 0.f, 0.f, 0.f};
#pragma unroll
    for (int kk = 0; kk < 4; ++kk)
      acc = __builtin_amdgcn_mfma_f32_16x16x32_bf16(af[kk], bv[kk], acc, 0, 0, 0);
    const int prow = w * 16 + r0l;
#pragma unroll
    for (int r = 0; r < 4; ++r) {
      size_t pp = (size_t)(pos0 + prow + r) * CD + d;
      out[pp] = (acc[r] + bo) * b2f(gate[pp]);
    }
  }
}

extern "C" void kernel_launch(void* const* d_in, const int* in_sizes, int n_in,
                              void* d_out, int out_size, void* d_ws, size_t ws_size,
                              hipStream_t stream) {
  (void)in_sizes; (void)n_in; (void)out_size; (void)ws_size;
  const float* act  = (const float*)d_in[0];
  const float* mask = (const float*)d_in[1];
  const float* lnw  = (const float*)d_in[2];
  const float* lnb  = (const float*)d_in[3];
  const float* lpw  = (const float*)d_in[4];
  const float* lpb  = (const float*)d_in[5];
  const float* rpw  = (const float*)d_in[6];
  const float* rpb  = (const float*)d_in[7];
  const float* lgw  = (const float*)d_in[8];
  const float* lgb  = (const float*)d_in[9];
  const float* rgw  = (const float*)d_in[10];
  const float* rgb  = (const float*)d_in[11];
  const float* clnw = (const float*)d_in[12];
  const float* clnb = (const float*)d_in[13];
  const float* opw  = (const float*)d_in[14];
  const float* opb  = (const float*)d_in[15];
  const float* glw  = (const float*)d_in[16];
  const float* glb  = (const float*)d_in[17];

  char* wsb = (char*)d_ws;
  u16* wb = (u16*)wsb;                       // 6 * 16384 * 2B = 196KB
  const size_t SZ = (size_t)NN * CD * 2;     // 151MB
  size_t off = (size_t)1 << 20;
  u16* left_t  = (u16*)(wsb + off); off += SZ;
  u16* right_t = (u16*)(wsb + off); off += SZ;
  u16* gate    = (u16*)(wsb + off); off += SZ;
  float* o1    = (float*)(wsb + off); off += SZ;   // f32 ch 0-63 (64*NN*4B = SZ)
  float* o2    = (float*)left_t;                    // f32 ch 64-95 over left_t ch 0-63 (dead)
  float* o3    = (float*)right_t;                   // f32 ch 96-127 over right_t ch 0-63 (dead)

  k_convw<<<384, 256, 0, stream>>>(lpw, lgw, rpw, rgw, glw, opw, wb);
  k_proj<<<NN / 128, 256, 0, stream>>>(act, mask, lnw, lnb, wb,
                                       lpb, lgb, rpb, rgb, glb,
                                       left_t, right_t, gate);
  // launch A: channels 0-63 (reads all of left/right ch 0-63, writes o1 only)
  k_tri<<<2304, 256, 0, stream>>>(left_t, right_t, o1, o2, o3, 0);
  // launch B: channels 64-127 (reads ch 64-127 halves; writes ch 0-63 halves — dead after A)
  k_tri<<<2304, 256, 0, stream>>>(left_t, right_t, o1, o2, o3, 64);
  k_post<<<NN / 64, 256, 0, stream>>>(o1, o2, o3, gate, clnw, clnb,
                                      wb + 5 * 16384, opb, (float*)d_out);
}